// Round 2
// baseline (367.753 us; speedup 1.0000x reference)
//
#include <hip/hip_runtime.h>
#include <math.h>

// Problem constants (from reference setup_inputs)
constexpr int B = 4;
constexpr int N = 512;     // rois per batch
constexpr int C = 256;     // channels
constexpr int H = 256;
constexpr int W = 256;
constexpr int NPT = 5;     // center, front, back, left, right
constexpr int PTS = N * NPT;           // 2560 sample points per batch
constexpr int CHUNKS = 8;              // point chunks per (b, channel-group)
constexpr int PCHUNK = PTS / CHUNKS;   // 320 points per block
constexpr int CG = 4;                  // channels per block (one per wave)
constexpr int NCG = C / CG;            // 64 channel groups
constexpr int NBLK = B * NCG * CHUNKS; // 2048 blocks

// xs = (x + 51.2) * 2.5

__global__ __launch_bounds__(256)
void bev_gather_kernel(const float* __restrict__ feats,  // (B,C,H,W)
                       const float* __restrict__ rois,   // (B,N,7)
                       float* __restrict__ out)          // (B,N,NPT*C)
{
    // XCD-aware swizzle: consecutive blockIdx round-robin XCDs (i%8).
    // Co-locate all 8 point-chunks of one (b,cg) group on the same nominal
    // XCD so its L2 absorbs cross-chunk line reuse within the 4 planes.
    const int i    = blockIdx.x;
    const int xcd  = i & 7;
    const int k    = i >> 3;                 // [0,256)
    const int grp  = xcd * 32 + (k & 31);    // [0,256) : (b,cg) id
    const int chunk= k >> 5;                 // [0,8)
    const int b    = grp >> 6;               // [0,4)
    const int cg   = grp & 63;               // [0,64)

    const int tid  = threadIdx.x;
    const int wave = tid >> 6;               // [0,4) -> channel within group
    const int lane = tid & 63;
    const int c    = cg * CG + wave;

    __shared__ float sxs[PCHUNK];
    __shared__ float sys[PCHUNK];
    __shared__ float svals[PCHUNK][CG + 1];  // +1 pad: phase-2 stride 5 mod 32 conflict-free

    const int qbase = chunk * PCHUNK;

    // ---- Phase 1: per-point geometry into LDS (point id q = n*NPT + p) ----
    for (int q = tid; q < PCHUNK; q += 256) {
        const int qq = qbase + q;
        const int n  = qq / NPT;
        const int p  = qq - n * NPT;
        const float* roi = rois + ((size_t)b * N + n) * 7;
        const float cx = roi[0], cy = roi[1];
        const float hx = 0.5f * roi[3];
        const float hy = 0.5f * roi[4];
        float si, co;
        sincosf(roi[6], &si, &co);
        // p: 0=center 1=front 2=back 3=left 4=right
        float px = cx, py = cy;
        if      (p == 1) { px = cx - hx * co; py = cy + hx * si; }
        else if (p == 2) { px = cx + hx * co; py = cy - hx * si; }
        else if (p == 3) { px = cx - hy * si; py = cy - hy * co; }
        else if (p == 4) { px = cx + hy * si; py = cy + hy * co; }
        sxs[q] = (px + 51.2f) * 2.5f;
        sys[q] = (py + 51.2f) * 2.5f;
    }
    __syncthreads();

    // ---- Phase 2: gather. Wave = one channel plane; lanes = 64 points. ----
    const float* __restrict__ fp = feats + ((size_t)b * C + c) * (H * W);

#pragma unroll
    for (int j = 0; j < PCHUNK / 64; ++j) {  // 5 iters, 20 loads in flight
        const int q = j * 64 + lane;
        const float xs = sxs[q];
        const float ys = sys[q];
        const float xf = floorf(xs);
        const float yf = floorf(ys);
        const int xi = (int)xf;
        const int yi = (int)yf;
        const int x0 = min(max(xi, 0), W - 1);
        const int x1 = min(max(xi + 1, 0), W - 1);
        const int y0 = min(max(yi, 0), H - 1);
        const int y1 = min(max(yi + 1, 0), H - 1);

        const float x0f = (float)x0, x1f = (float)x1;
        const float y0f = (float)y0, y1f = (float)y1;
        const float wa = (x1f - xs) * (y1f - ys);
        const float wb = (x1f - xs) * (ys - y0f);
        const float wc = (xs - x0f) * (y1f - ys);
        const float wd = (xs - x0f) * (ys - y0f);

        const float Ia = fp[y0 * W + x0];
        const float Ib = fp[y1 * W + x0];
        const float Ic = fp[y0 * W + x1];
        const float Id = fp[y1 * W + x1];

        svals[q][wave] = Ia * wa + Ib * wb + Ic * wc + Id * wd;
    }
    __syncthreads();

    // ---- Phase 3: 16B-per-point coalesced stores ----
    for (int q = tid; q < PCHUNK; q += 256) {
        const int qq = qbase + q;
        const int n  = qq / NPT;
        const int p  = qq - n * NPT;
        float4 v = make_float4(svals[q][0], svals[q][1], svals[q][2], svals[q][3]);
        float* op = out + (((size_t)(b * N + n) * NPT + p) * C + cg * CG);
        *reinterpret_cast<float4*>(op) = v;
    }
}

extern "C" void kernel_launch(void* const* d_in, const int* in_sizes, int n_in,
                              void* d_out, int out_size, void* d_ws, size_t ws_size,
                              hipStream_t stream) {
    const float* feats = (const float*)d_in[0];  // (B,C,H,W) f32
    const float* rois  = (const float*)d_in[1];  // (B,N,7)   f32
    float* out = (float*)d_out;                  // (B,N,NPT*C) f32

    bev_gather_kernel<<<dim3(NBLK), dim3(256), 0, stream>>>(feats, rois, out);
}